// Round 11
// baseline (621.802 us; speedup 1.0000x reference)
//
#include <hip/hip_runtime.h>
#include <hip/hip_bf16.h>
#include <math.h>

// ReformerAttention (LSH attention) on MI355X — MFMA + parallel sort + f64-MFMA bucket.
// B=4 T=4096 HID=768 H=12 D=64 n_hashes=2 n_buckets=32 bucket=128.
//
// Output projections are FOLDED: (attn@Wto^T+bto)@Wo^T+bo == attn@(Wo·Wto)^T
// + (Wo·bto+bo). Wcomb computed by the MFMA GEMM itself (Wo_bf16 @ WtoT_bf16,
// f32 accum); bcomb f32 from raw weights.
//
// Workspace layout (bytes), peak 103,809,280:
//   0           flag   256
//   256         stick  u16[48][8192]        786,432
//   786,688     lse_r  f32[48*2][4096]    1,572,864
//   2,359,552   nk     f32[48][4096]        786,432
//   3,145,984   qk     bf16[48][4096][64] 25,165,824  (after k_attn: Wcomb/bcomb/Wob/WtoT)
//   28,311,808  v      bf16[48][4096][64] 25,165,824  (later attn)
//   53,477,632  o_r    bf16[96][4096][64] 50,331,648
//   overlays inside o_r (dead before k_attn): WrotT/cls/Wqkb/Wvb/Xb

typedef __attribute__((ext_vector_type(8))) short bf16x8;
typedef __attribute__((ext_vector_type(4))) float f32x4;
typedef __attribute__((ext_vector_type(4))) double f64x4;

__device__ __forceinline__ float bf_lo(unsigned int w) { return __uint_as_float(w << 16); }
__device__ __forceinline__ float bf_hi(unsigned int w) { return __uint_as_float(w & 0xffff0000u); }
__device__ __forceinline__ float load_in(const void* p, size_t i, bool f32) {
  return f32 ? ((const float*)p)[i]
             : __bfloat162float(((const __hip_bfloat16*)p)[i]);
}
__device__ __forceinline__ unsigned short f2bf(float x) {
  __hip_bfloat16 h = __float2bfloat16(x);
  return *reinterpret_cast<unsigned short*>(&h);
}
__device__ __forceinline__ float bf2f(unsigned short u) { return __uint_as_float(((unsigned int)u) << 16); }

// ---------------------------------------------------------------- dtype detect
__global__ void k_detect(const unsigned int* __restrict__ X, int* __restrict__ flag) {
  if (threadIdx.x == 0 && blockIdx.x == 0) {
    int vote = 0;
    for (int i = 0; i < 64; ++i) {
      unsigned int e = (X[i] >> 7) & 0xffu;
      vote += (e >= 100u && e <= 141u) ? 1 : 0;
    }
    *flag = (vote < 32) ? 1 : 0;   // 1 => inputs are f32
  }
}

// ---------------------------------------------------------------- convert input -> bf16 (x8 vectorized)
__global__ __launch_bounds__(256) void k_convert(
    const void* __restrict__ src, unsigned short* __restrict__ dst, int n8,
    const int* __restrict__ flag) {
  const bool f32in = (*flag != 0);
  int i = blockIdx.x * 256 + threadIdx.x;
  if (i >= n8) return;
  if (f32in) {
    const float4* s = (const float4*)src + (size_t)i * 2;
    float4 a = s[0], b = s[1];
    union { unsigned short u[8]; uint4 v; } o;
    o.u[0] = f2bf(a.x); o.u[1] = f2bf(a.y); o.u[2] = f2bf(a.z); o.u[3] = f2bf(a.w);
    o.u[4] = f2bf(b.x); o.u[5] = f2bf(b.y); o.u[6] = f2bf(b.z); o.u[7] = f2bf(b.w);
    ((uint4*)dst)[i] = o.v;
  } else {
    ((uint4*)dst)[i] = ((const uint4*)src)[i];
  }
}

// ---------------------------------------------------------------- transpose + convert (Wto -> WtoT bf16)
__global__ __launch_bounds__(256) void k_transpose_cvt(
    const void* __restrict__ Wto, unsigned short* __restrict__ WtoT,
    const int* __restrict__ flag) {
  const bool f32in = (*flag != 0);
  __shared__ unsigned short T[64][65];
  const int bx = blockIdx.x % 12, by = blockIdx.x / 12;
  const int p0 = by * 64, n0 = bx * 64;
  const int rw = threadIdx.x >> 6, lane = threadIdx.x & 63;
  #pragma unroll
  for (int pass = 0; pass < 16; ++pass) {
    int row = pass * 4 + rw;
    T[row][lane] = f2bf(load_in(Wto, (size_t)(p0 + row) * 768 + n0 + lane, f32in));
  }
  __syncthreads();
  #pragma unroll
  for (int pass = 0; pass < 16; ++pass) {
    int row = pass * 4 + rw;
    WtoT[(size_t)(n0 + row) * 768 + p0 + lane] = T[lane][row];
  }
}

// ---------------------------------------------------------------- folded bias (f32, raw weights)
__global__ __launch_bounds__(256) void k_bias_fold(
    const void* __restrict__ Wo, const void* __restrict__ bto,
    const void* __restrict__ bo, float* __restrict__ bcomb,
    const int* __restrict__ flag) {
  const bool f32in = (*flag != 0);
  const int n = blockIdx.x * 4 + (threadIdx.x >> 6);
  const int lane = threadIdx.x & 63;
  float s = 0.f;
  #pragma unroll
  for (int i = 0; i < 12; ++i) {
    int j = lane + i * 64;
    s = fmaf(load_in(Wo, (size_t)n * 768 + j, f32in), load_in(bto, j, f32in), s);
  }
  #pragma unroll
  for (int off = 1; off < 64; off <<= 1) s += __shfl_xor(s, off, 64);
  if (lane == 0) bcomb[n] = s + load_in(bo, n, f32in);
}

// ---------------------------------------------------------------- fold rotations (f64)
__global__ __launch_bounds__(256) void k_build_wrot(
    const void* __restrict__ Wqk, const void* __restrict__ rot,
    double* __restrict__ WrotT, const int* __restrict__ flag) {
  const bool f32in = (*flag != 0);
  int idx = blockIdx.x * 256 + threadIdx.x;
  if (idx >= 768 * 384) return;
  int row = idx % 384;
  int c   = idx / 384;
  int hh = row >> 5, hi = row & 31;
  double s = 0.0;
  for (int f = 0; f < 64; ++f) {
    double rv = (double)load_in(rot, f * 32 + hi, f32in);
    double wv = (double)load_in(Wqk, (size_t)(hh * 64 + f) * 768 + c, f32in);
    s = fma(rv, wv, s);
  }
  WrotT[(size_t)c * 384 + row] = s;
}

// ---------------------------------------------------------------- bucket scores (f64 MFMA GEMM) + argmax
// v5: LDS-BW relief. Rounds 2-4 were LDS-BW-bound (~156 B/cy demand vs 128
// peak: 28 x 512B LDS reads + staging per wave per K-step). The f64 A-frag is
// ONE f64/lane, so A is now loaded DIRECTLY from global (depth-1 register
// prefetch, 4 scalar loads/thread/step; each 64B line fully consumed across
// the 4 kq's; X panel L1/L2-hot). W keeps the round-2 LDS double-buffer
// (1 barrier/step). LDS demand drops to ~110 B/cy. Values and accumulation
// order are BIT-IDENTICAL to round 2 (same k-order, same f32->f64 widening).
// BM=128 BN=96 BK=16, 512 thr = 8 waves, wave w rows [w*16,w*16+16) x 96 cols,
// acc = 6 x double4, grid 128x4. LDS = Sc-union 50.7 KB -> 2 blocks/CU.
//
// D-layout determined at RUNTIME by two probe MFMAs (rowid/colid per acc
// register) — the f64 16x16x4 C/D register mapping is not among the
// HW-verified gfx950 layouts and the assumed mapping failed in round 0.
__global__ __launch_bounds__(512) void k_bucket(
    const void* __restrict__ X, const double* __restrict__ WrotT,
    unsigned char* __restrict__ cls, const int* __restrict__ flag) {
  const bool f32in = (*flag != 0);
  __shared__ double SH[6336];          // 50,688 B
  // W staging: Ws[b] = SH + b*1568  ([16][98], [k][n]);  Sc = SH ([96][66])
  double* Sc = SH;
  const int tid = threadIdx.x;
  const int M0 = blockIdx.x * 128;
  const int N0 = blockIdx.y * 96;
  const int w = tid >> 6, lane = tid & 63;
  const int l15 = lane & 15, lq = lane >> 4;
  const int wk = tid >> 5, wn3 = (tid & 31) * 3;   // W staging: k-row, 3-col group

  f64x4 acc[6];
  #pragma unroll
  for (int j = 0; j < 6; ++j) acc[j] = (f64x4){0.0, 0.0, 0.0, 0.0};

  // ---- runtime D-layout probe (layout-agnostic epilogue) ----
  int rowid[4], colid[4];
  {
    f64x4 zz = (f64x4){0.0, 0.0, 0.0, 0.0};
    f64x4 pr = __builtin_amdgcn_mfma_f64_16x16x4f64(
        (double)l15, (lq == 0) ? 1.0 : 0.0, zz, 0, 0, 0);
    f64x4 pc = __builtin_amdgcn_mfma_f64_16x16x4f64(
        (lq == 0) ? 1.0 : 0.0, (double)l15, zz, 0, 0, 0);
    #pragma unroll
    for (int r = 0; r < 4; ++r) {
      rowid[r] = (int)pr[r];
      colid[r] = (int)pc[r];
    }
  }

  // ---- A: direct-from-global, depth-1 register prefetch (4 scalars) ----
  const int aoff0 = (M0 + w * 16 + l15) * 768 + lq;   // + t*16 + kq*4
  float av[4];
  auto load_a = [&](int t) {
    #pragma unroll
    for (int kq = 0; kq < 4; ++kq) {
      int off = aoff0 + t * 16 + kq * 4;
      av[kq] = f32in ? ((const float*)X)[off]
                     : bf2f(((const unsigned short*)X)[off]);
    }
  };
  // ---- W: register prefetch -> LDS double buffer (round-2 pattern) ----
  double wvv[3];
  auto load_w = [&](int k0) {
    const double* wp = WrotT + (size_t)(k0 + wk) * 384 + N0 + wn3;
    wvv[0] = wp[0]; wvv[1] = wp[1]; wvv[2] = wp[2];
  };
  auto store_w = [&](int bsel) {
    double* Ws = SH + bsel * 1568;
    Ws[wk * 98 + wn3]     = wvv[0];
    Ws[wk * 98 + wn3 + 1] = wvv[1];
    Ws[wk * 98 + wn3 + 2] = wvv[2];
  };

  load_w(0);
  store_w(0);
  load_a(0);
  __syncthreads();
  for (int t = 0; t < 48; ++t) {
    const double* Ws = SH + (t & 1) * 1568;
    if (t < 47) load_w((t + 1) * 16);
    float ac[4];
    #pragma unroll
    for (int kq = 0; kq < 4; ++kq) ac[kq] = av[kq];
    if (t < 47) load_a(t + 1);
    #pragma unroll
    for (int kq = 0; kq < 4; ++kq) {
      // A frag: lane holds X[row = M0 + w*16 + l15][k = t*16 + kq*4 + lq]
      double a = (double)ac[kq];
      // B frag: lane holds WrotT[k][col = N0 + nt*16 + l15]
      const double* wr = &Ws[(kq * 4 + lq) * 98 + l15];
      #pragma unroll
      for (int nt = 0; nt < 6; ++nt)
        acc[nt] = __builtin_amdgcn_mfma_f64_16x16x4f64(a, wr[nt * 16], acc[nt], 0, 0, 0);
    }
    if (t < 47) store_w((t & 1) ^ 1);
    __syncthreads();
  }

  // epilogue: two 64-token chunks through Sc, then first-index-wins argmax.
  #pragma unroll
  for (int chunk = 0; chunk < 2; ++chunk) {
    __syncthreads();
    if ((w >> 2) == chunk) {
      int lr = (w & 3) * 16;
      #pragma unroll
      for (int nt = 0; nt < 6; ++nt)
        #pragma unroll
        for (int r = 0; r < 4; ++r)
          Sc[(nt * 16 + colid[r]) * 66 + lr + rowid[r]] = acc[nt][r];
    }
    __syncthreads();
    for (int task = tid; task < 384; task += 512) {
      int g = task >> 6, tok = task & 63;
      const double* s = &Sc[(g * 16) * 66 + tok];
      double mx = -1.0e300;
      #pragma unroll
      for (int i = 0; i < 16; ++i) {
        double a = s[i * 66];
        mx = fmax(mx, fmax(a, -a));
      }
      int amax = 0;
      #pragma unroll
      for (int i = 15; i >= 0; --i) if (-s[i * 66] == mx) amax = 16 + i;
      #pragma unroll
      for (int i = 15; i >= 0; --i) if (s[i * 66] == mx) amax = i;
      int m = M0 + chunk * 64 + tok;
      int b = m >> 12, t = m & 4095;
      int gg = blockIdx.y * 6 + g, hh = gg >> 1, h = gg & 1;
      cls[(size_t)(b * 12 + hh) * 8192 + h * 4096 + t] = (unsigned char)(h * 32 + amax);
    }
  }
}

// ---------------------------------------------------------------- parallel stable counting sort
__global__ __launch_bounds__(1024) void k_sort(
    const unsigned char* __restrict__ clsg,
    unsigned short* __restrict__ stick) {
  __shared__ unsigned short cntg[128 * 64];
  __shared__ int classbase[64];
  const int row = blockIdx.x;
  const int tid = threadIdx.x;
  const int wave = tid >> 6, lane = tid & 63;
  const unsigned char* cr = clsg + ((size_t)row << 13);

  for (int i = tid; i < 128 * 64 / 2; i += 1024) ((uint32_t*)cntg)[i] = 0;
  __syncthreads();

  unsigned char myc[8], myrank[8];
  const unsigned long long ltmask = (lane == 0) ? 0ull : (~0ull >> (64 - lane));
  #pragma unroll
  for (int chunk = 0; chunk < 8; ++chunk) {
    int g = chunk * 16 + wave;
    int j = g * 64 + lane;
    int c = cr[j];
    unsigned long long same = ~0ull;
    #pragma unroll
    for (int bit = 0; bit < 6; ++bit) {
      unsigned long long bm = __ballot((c >> bit) & 1);
      same &= ((c >> bit) & 1) ? bm : ~bm;
    }
    int rank = __popcll(same & ltmask);
    if (rank == 0) cntg[g * 64 + c] = (unsigned short)__popcll(same);
    myc[chunk] = (unsigned char)c;
    myrank[chunk] = (unsigned char)rank;
  }
  __syncthreads();
  if (tid < 64) {
    int run = 0;
    for (int g = 0; g < 128; ++g) {
      int t = cntg[g * 64 + tid];
      cntg[g * 64 + tid] = (unsigned short)run;
      run += t;
    }
    classbase[tid] = run;
  }
  __syncthreads();
  if (tid == 0) {
    int run = 0;
    for (int c = 0; c < 64; ++c) { int t = classbase[c]; classbase[c] = run; run += t; }
  }
  __syncthreads();
  unsigned short* out = stick + ((size_t)row << 13);
  #pragma unroll
  for (int chunk = 0; chunk < 8; ++chunk) {
    int g = chunk * 16 + wave;
    int j = g * 64 + lane;
    int c = myc[chunk];
    int pos = classbase[c] + cntg[g * 64 + c] + myrank[chunk];
    out[pos] = (unsigned short)j;
  }
}

// ---------------------------------------------------------------- MFMA GEMM, K=768
// Round-6 form (best measured): padded LDS [128][40], depth-1 register
// prefetch. bias (when non-null) is ALWAYS f32.
__global__ __launch_bounds__(256) void k_gemm_mfma(
    const unsigned short* __restrict__ A, const unsigned short* __restrict__ W,
    const float* __restrict__ bias, void* __restrict__ Cout,
    int layout, int out_ext, const int* __restrict__ flag) {
  const bool f32in = (*flag != 0);
  const bool oF32 = out_ext && f32in;
  __shared__ unsigned short As[128 * 40];
  __shared__ unsigned short Bs[128 * 40];
  const int tid = threadIdx.x;
  const int bm = blockIdx.x, bn = blockIdx.y;
  const int w = tid >> 6, lane = tid & 63;
  const int l15 = lane & 15, lq = lane >> 4;
  const int wm = (w >> 1) * 64, wn = (w & 1) * 64;
  const int r4 = tid >> 2, c4 = tid & 3;
  const unsigned short* Ag = A + (size_t)(bm * 128 + r4) * 768 + c4 * 8;
  const unsigned short* Bg = W + (size_t)(bn * 128 + r4) * 768 + c4 * 8;
  f32x4 acc[4][4];
  #pragma unroll
  for (int i = 0; i < 4; ++i)
    #pragma unroll
    for (int j = 0; j < 4; ++j) acc[i][j] = (f32x4){0.f, 0.f, 0.f, 0.f};
  uint4 pa0 = *(const uint4*)(Ag);
  uint4 pa1 = *(const uint4*)(Ag + 64 * 768);
  uint4 pb0 = *(const uint4*)(Bg);
  uint4 pb1 = *(const uint4*)(Bg + 64 * 768);
  for (int kt = 0; kt < 24; ++kt) {
    __syncthreads();
    *(uint4*)&As[r4 * 40 + c4 * 8] = pa0;
    *(uint4*)&As[(r4 + 64) * 40 + c4 * 8] = pa1;
    *(uint4*)&Bs[r4 * 40 + c4 * 8] = pb0;
    *(uint4*)&Bs[(r4 + 64) * 40 + c4 * 8] = pb1;
    __syncthreads();
    if (kt < 23) {
      int off = (kt + 1) * 32;
      pa0 = *(const uint4*)(Ag + off);
      pa1 = *(const uint4*)(Ag + 64 * 768 + off);
      pb0 = *(const uint4*)(Bg + off);
      pb1 = *(const uint4*)(Bg + 64 * 768 + off);
    }
    bf16x8 af[4], bfr[4];
    #pragma unroll
    for (int mt = 0; mt < 4; ++mt)
      af[mt] = *(const bf16x8*)&As[(wm + mt * 16 + l15) * 40 + lq * 8];
    #pragma unroll
    for (int nt = 0; nt < 4; ++nt)
      bfr[nt] = *(const bf16x8*)&Bs[(wn + nt * 16 + l15) * 40 + lq * 8];
    #pragma unroll
    for (int mt = 0; mt < 4; ++mt)
      #pragma unroll
      for (int nt = 0; nt < 4; ++nt)
        acc[mt][nt] = __builtin_amdgcn_mfma_f32_16x16x32_bf16(af[mt], bfr[nt], acc[mt][nt], 0, 0, 0);
  }
  #pragma unroll
  for (int mt = 0; mt < 4; ++mt) {
    #pragma unroll
    for (int nt = 0; nt < 4; ++nt) {
      #pragma unroll
      for (int reg = 0; reg < 4; ++reg) {
        int m = bm * 128 + wm + mt * 16 + lq * 4 + reg;
        int n = bn * 128 + wn + nt * 16 + l15;
        float val = acc[mt][nt][reg];
        if (bias != nullptr) val += bias[n];
        if (layout == 0) {
          size_t addr = (size_t)m * 768 + n;
          if (oF32) ((float*)Cout)[addr] = val;
          else      ((unsigned short*)Cout)[addr] = f2bf(val);
        } else {
          int b2 = m >> 12, t2 = m & 4095, hh = n >> 6, f = n & 63;
          ((unsigned short*)Cout)[((((size_t)(b2 * 12 + hh)) << 12) + t2) * 64 + f] = f2bf(val);
        }
      }
    }
  }
}

// ---------------------------------------------------------------- key norms
__global__ __launch_bounds__(256) void k_norm(
    const unsigned short* __restrict__ qk, float* __restrict__ nk) {
  int row = blockIdx.x * 32 + (threadIdx.x >> 3);
  int cs = threadIdx.x & 7;
  const uint4* p = (const uint4*)(qk + (size_t)row * 64);
  uint4 wv = p[cs];
  float s = 0.f;
  float e;
  e = bf_lo(wv.x); s += e * e;  e = bf_hi(wv.x); s += e * e;
  e = bf_lo(wv.y); s += e * e;  e = bf_hi(wv.y); s += e * e;
  e = bf_lo(wv.z); s += e * e;  e = bf_hi(wv.z); s += e * e;
  e = bf_lo(wv.w); s += e * e;  e = bf_hi(wv.w); s += e * e;
  s += __shfl_xor(s, 1, 64);
  s += __shfl_xor(s, 2, 64);
  s += __shfl_xor(s, 4, 64);
  if (cs == 0) nk[row] = 1.0f / fmaxf(sqrtf(s), 1e-12f);
}

// ---------------------------------------------------------------- MFMA LSH attention
// Q-hoist + LDS aliasing for occupancy: Q fragments are loop-invariant, so
// they are read into 16 VGPRs once after Q staging; the Qs LDS region is then
// reused as Ps/Vs. LDS 37.5 KB => 4 blocks/CU. MFMA order bit-identical.
__global__ __launch_bounds__(256) void k_attn_mfma(
    const unsigned short* __restrict__ qk,
    const unsigned short* __restrict__ vv,
    const unsigned short* __restrict__ stick,
    const void* __restrict__ mask,
    const float* __restrict__ nk,
    unsigned short* __restrict__ o_r,
    float* __restrict__ lse_r,
    const int* __restrict__ flag) {
  const bool f32in = (*flag != 0);
  __shared__ unsigned short QPs[128 * 72];   // Q staging, then P matrix / V staging
  __shared__ unsigned short Ks[64 * 72];
  __shared__ unsigned short Vt[64 * 72];
  __shared__ unsigned short Tq[128];
  __shared__ unsigned short Tkv[64];
  __shared__ float Nkv[64];
  unsigned short* Qs = QPs;
  unsigned short* Ps = QPs;
  unsigned short* Vs = QPs;

  const int tid = threadIdx.x;
  const int bh = blockIdx.x >> 6;
  const int ci = blockIdx.x & 63;
  const int b  = bh / 12;
  const int prev = (ci + 63) & 63;
  const int w = tid >> 6, lane = tid & 63;
  const int l15 = lane & 15, lq = lane >> 4;
  const unsigned short* srow = stick + ((size_t)bh << 13);
  const int jrow = tid >> 3, cs = tid & 7;

  #pragma unroll
  for (int pass = 0; pass < 4; ++pass) {
    int r = jrow + pass * 32;
    int s = srow[ci * 128 + r];
    int t = s & 4095;
    uint4 qw = ((const uint4*)(qk + ((((size_t)bh << 12) + t) << 6)))[cs];
    *(uint4*)&Qs[r * 72 + cs * 8] = qw;
    if (cs == 0) {
      float mv = load_in(mask, b * 4096 + t, f32in);
      Tq[r] = (unsigned short)(s | ((mv != 0.0f) ? 0 : 0x8000));
    }
  }
  __syncthreads();

  // ---- Q-hoist: loop-invariant Q fragments into registers ----
  bf16x8 qf[2][2];   // [ks][mt]
  #pragma unroll
  for (int ks = 0; ks < 2; ++ks)
    #pragma unroll
    for (int mt = 0; mt < 2; ++mt)
      qf[ks][mt] = *(const bf16x8*)&Qs[(w * 32 + mt * 16 + l15) * 72 + ks * 32 + lq * 8];

  unsigned short tqr[2][4];
  #pragma unroll
  for (int mt = 0; mt < 2; ++mt)
    #pragma unroll
    for (int reg = 0; reg < 4; ++reg)
      tqr[mt][reg] = Tq[w * 32 + mt * 16 + lq * 4 + reg];

  float m_run[2][4], l_run[2][4];
  f32x4 oacc[2][4];
  #pragma unroll
  for (int mt = 0; mt < 2; ++mt)
    #pragma unroll
    for (int reg = 0; reg < 4; ++reg) { m_run[mt][reg] = -3.0e38f; l_run[mt][reg] = 0.0f; }
  #pragma unroll
  for (int mt = 0; mt < 2; ++mt)
    #pragma unroll
    for (int nto = 0; nto < 4; ++nto) oacc[mt][nto] = (f32x4){0.f, 0.f, 0.f, 0.f};

  for (int kt = 0; kt < 4; ++kt) {
    __syncthreads();   // all waves done with Qs fragments (kt=0) / prev Ps+Vt (kt>0)
    #pragma unroll
    for (int pass = 0; pass < 2; ++pass) {
      int j = jrow + pass * 32;
      int chunk = (kt < 2) ? ci : prev;
      int s = srow[chunk * 128 + (kt & 1) * 64 + j];
      int t = s & 4095;
      const uint4* kb = (const uint4*)(qk + ((((size_t)bh << 12) + t) << 6));
      *(uint4*)&Ks[j * 72 + cs * 8] = kb[cs];
      const uint4* vb = (const uint4*)(vv + ((((size_t)bh << 12) + t) << 6));
      int sw = (cs ^ (j & 7) ^ (j >> 3)) & 7;
      *(uint4*)&Vs[j * 72 + sw * 8] = vb[cs];
      if (cs == 0) {
        float mv = load_in(mask, b * 4096 + t, f32in);
        Tkv[j] = (unsigned short)(t | ((mv != 0.0f) ? 0 : 0x8000));
        Nkv[j] = nk[((size_t)bh << 12) + t] * 0.125f;
      }
    }
    __syncthreads();

    #pragma unroll
    for (int i = 0; i < 8; ++i) {
      int cp = w * 8 + i;
      int q8 = cp >> 2;
      int sw = (q8 ^ (lane & 7) ^ (lane >> 3)) & 7;
      uint32_t wv = *(const uint32_t*)&Vs[lane * 72 + sw * 8 + ((2 * cp) & 7)];
      Vt[(2 * cp) * 72 + lane]     = (unsigned short)(wv & 0xffff);
      Vt[(2 * cp + 1) * 72 + lane] = (unsigned short)(wv >> 16);
    }

    f32x4 sacc[2][4];
    #pragma unroll
    for (int mt = 0; mt < 2; ++mt)
      #pragma unroll
      for (int nt = 0; nt < 4; ++nt) sacc[mt][nt] = (f32x4){0.f, 0.f, 0.f, 0.f};
    #pragma unroll
    for (int ks = 0; ks < 2; ++ks) {
      #pragma unroll
      for (int nt = 0; nt < 4; ++nt) {
        bf16x8 bfr = *(const bf16x8*)&Ks[(nt * 16 + l15) * 72 + ks * 32 + lq * 8];
        #pragma unroll
        for (int mt = 0; mt < 2; ++mt)
          sacc[mt][nt] = __builtin_amdgcn_mfma_f32_16x16x32_bf16(qf[ks][mt], bfr, sacc[mt][nt], 0, 0, 0);
      }
    }

    unsigned short tkc[4];
    float nkc[4];
    #pragma unroll
    for (int nt = 0; nt < 4; ++nt) {
      tkc[nt] = Tkv[nt * 16 + l15];
      nkc[nt] = Nkv[nt * 16 + l15];
    }
    float dv[2][4][4];
    #pragma unroll
    for (int mt = 0; mt < 2; ++mt)
      #pragma unroll
      for (int nt = 0; nt < 4; ++nt)
        #pragma unroll
        for (int reg = 0; reg < 4; ++reg) {
          float x = sacc[mt][nt][reg] * nkc[nt];
          unsigned short ts = tqr[mt][reg];
          if (((tkc[nt] | ts) & 0x8000) != 0) x = -1.0e9f;
          if (((tkc[nt] ^ ts) & 0x0fff) == 0) x = -5.0e4f;
          dv[mt][nt][reg] = x;
        }
    float mn[2][4], scv[2][4];
    #pragma unroll
    for (int mt = 0; mt < 2; ++mt)
      #pragma unroll
      for (int reg = 0; reg < 4; ++reg) {
        float rm = fmaxf(fmaxf(dv[mt][0][reg], dv[mt][1][reg]),
                         fmaxf(dv[mt][2][reg], dv[mt][3][reg]));
        rm = fmaxf(rm, __shfl_xor(rm, 1, 64));
        rm = fmaxf(rm, __shfl_xor(rm, 2, 64));
        rm = fmaxf(rm, __shfl_xor(rm, 4, 64));
        rm = fmaxf(rm, __shfl_xor(rm, 8, 64));
        float mnew = fmaxf(m_run[mt][reg], rm);
        scv[mt][reg] = __expf(m_run[mt][reg] - mnew);
        m_run[mt][reg] = mnew;
        mn[mt][reg] = mnew;
      }
    #pragma unroll
    for (int mt = 0; mt < 2; ++mt)
      #pragma unroll
      for (int nt = 0; nt < 4; ++nt)
        #pragma unroll
        for (int reg = 0; reg < 4; ++reg)
          dv[mt][nt][reg] = __expf(dv[mt][nt][reg] - mn[mt][reg]);
    #pragma unroll
    for (int mt = 0; mt < 2; ++mt)
      #pragma unroll
      for (int reg = 0; reg < 4; ++reg) {
        float rs = ((dv[mt][0][reg] + dv[mt][1][reg]) + (dv[mt][2][reg] + dv[mt][3][reg]));
        rs += __shfl_xor(rs, 1, 64);
        rs += __shfl_xor(rs, 2, 64);
        rs += __shfl_xor(rs, 4, 64);
        rs += __shfl_xor(rs, 8, 64);
        l_run[mt][reg] = l_run[mt][reg] * scv[mt][reg] + rs;
      }
    #pragma unroll
    for (int mt = 0; mt < 2; ++mt)
      #pragma unroll
      for (int nto = 0; nto < 4; ++nto)
        #pragma unroll
        for (int reg = 0; reg < 4; ++reg)
          oacc[mt][nto][reg] *= scv[mt][reg];

    __syncthreads();

    #pragma unroll
    for (int mt = 0; mt < 2; ++mt)
      #pragma unroll
      for (int nt = 0; nt < 4; ++nt)
        #pragma unroll
        for (int reg = 0; reg < 4; ++reg)
          Ps[w * 2304 + (mt * 16 + lq * 4 + reg) * 72 + nt * 16 + l15] = f2bf(dv[mt][nt][reg]);

    #pragma unroll
    for (int ks = 0; ks < 2; ++ks) {
      bf16x8 pf[2];
      #pragma unroll
      for (int mt = 0; mt < 2; ++mt)
        pf[mt] = *(const bf16x8*)&Ps[w * 2304 + (mt * 16 + l15) * 72 + ks * 32 + lq * 8];
      #pragma unroll
      for (int nto = 0; nto < 4; ++nto) {
        bf16x8 vf = *(const bf16x8*)&Vt[(nto * 16 + l15) * 72 + ks * 32 + lq * 8];
        #pragma unroll
        for (int mt = 0; mt < 2; ++mt)
          oacc[mt][nto] = __builtin_amdgcn_mfma_f32_16x16x32_bf16(pf[mt], vf, oacc[mt][nto], 0, 0, 0);
      }
    }
  }

  float invl[2][4];
  #pragma unroll
  for (int mt = 0; mt < 2; ++mt)
    #pragma unroll
    for (int reg = 0; reg < 4; ++reg) {
      float lr = l_run[mt][reg];
      invl[mt][reg] = 1.0f / lr;
      if (l15 == 0) {
        int Rr = w * 32 + mt * 16 + lq * 4 + reg;
        int s = Tq[Rr];
        int tq0 = s & 4095, rq0 = (s >> 12) & 1;
        lse_r[(((size_t)(bh * 2 + rq0)) << 12) + tq0] = m_run[mt][reg] + __logf(lr);
      }
    }
  #pragma unroll
  for (int mt = 0; mt < 2; ++mt)
    #pragma unroll
    for (int nto = 0; nto < 4; ++nto)
      #pragma unroll
      for (int reg = 0; reg < 4; ++reg)
        Ps[w * 2304 + (mt * 16 + lq * 4 + reg) * 72 + nto * 16 + l15] =
            f2bf(oacc[mt][nto][reg] * invl[mt][reg]);
  #pragma unroll
  for (int pass = 0; pass < 4; ++pass) {
    int rl = pass * 8 + (lane >> 3);
    int s = Tq[w * 32 + rl];
    int tq0 = s & 4095, rq0 = (s >> 12) & 1;
    uint4 ov = *(const uint4*)&Ps[w * 2304 + rl * 72 + (lane & 7) * 8];
    *(uint4*)(o_r + ((((size_t)(bh * 2 + rq0)) << 12) + tq0) * 64 + (lane & 7) * 8) = ov;
  }
}

// ---------------------------------------------------------------- combine hash rounds (x8 vectorized)
__global__ __launch_bounds__(256) void k_combine(
    const unsigned short* __restrict__ o_r,
    const float* __restrict__ lse_r,
    unsigned short* __restrict__ attn) {
  int idx = blockIdx.x * 256 + threadIdx.x;   // over 48*4096*8 groups
  if (idx >= 48 * 4096 * 8) return;
  int f8 = idx & 7;
  int t = (idx >> 3) & 4095;
  int bh = idx >> 15;
  float l0 = lse_r[((size_t)(bh * 2 + 0) << 12) + t];
  float l1 = lse_r[((size_t)(bh * 2 + 1) << 12) + t];
  float mm = fmaxf(l0, l1);
  float e0 = __expf(l0 - mm), e1 = __expf(l1 - mm);
  float inv = 1.0f / (e0 + e1);
  float c0 = e0 * inv, c1 = e1 * inv;
  uint4 v0 = *(const uint4*)(o_r + ((((size_t)(bh * 2 + 0)) << 12) + t) * 64 + f8 * 8);
  uint4 v1 = *(const uint4*)(o_r + ((((size_t)(bh * 2 + 1)) << 12) + t) * 64 + f8 * 8);
  union { unsigned short u[8]; uint4 v; } o;
  const unsigned int* a0 = (const unsigned int*)&v0;
  const unsigned int* a1 = (const unsigned int*)&v1;
  #pragma unroll
  for (int j = 0; j < 4; ++j) {
    float lo = c0 * bf_lo(a0[j]) + c1 * bf_lo(a1[j]);
    float hi = c0 * bf_hi(a0[j]) + c1 * bf_hi(a1[j]);
    o.u[2 * j]     = f2bf(lo);
    o.u[2 * j + 1] = f2bf(hi);
  }
  int b = bh / 12, hh = bh % 12;
  *(uint4*)(attn + ((size_t)(b * 4096 + t)) * 768 + hh * 64 + f8 * 8) = o.v;
}

extern "C" void kernel_launch(void* const* d_in, const int* in_sizes, int n_in,
                              void* d_out, int out_size, void* d_ws, size_t ws_size,
                              hipStream_t stream) {
  (void)in_sizes; (void)n_in; (void)out_size; (void)ws_size;
  const void* X    = d_in[0];
  const void* mask = d_in[1];
  const void* Wqk  = d_in[2];
  const void* Wv   = d_in[3];
  const void* rot  = d_in[4];
  const void* Wto  = d_in[5];
  const void* bto  = d_in[6];
  const void* Wo   = d_in[7];
  const void* bo   = d_in[8];

  char* ws = (char*)d_ws;
  int*            flag  = (int*)(ws);
  unsigned short* stick = (unsigned short*)(ws + 256);
  float*          lse_r = (float*)(ws + 786688);
  float*          nk    = (float*)(ws + 2359552);
  unsigned short* qk    = (unsigned short*)(ws + 3145984);
  unsigned short* v     = (unsigned short*)(ws + 28311808);
  unsigned short* o_r   = (unsigned short*)(ws + 53477632);
  double*         WrotT = (double*)(ws + 53477632);
  unsigned char*  cls   = (unsigned char*)(ws + 55836928);
  unsigned short* Wqkb  = (unsigned short*)(ws + 56230144);
  unsigned short* Wvb   = (unsigned short*)(ws + 57409792);
  unsigned short* Xb    = (unsigned short*)(ws + 58589440);
  unsigned short* attn  = v;
  // fold scratch lives in the dead qk region after k_attn
  unsigned short* Wcomb = (unsigned short*)(ws + 3145984);               // 1,179,648
  float*          bcomb = (float*)(ws + 3145984 + 1179648);              //     3,072
  unsigned short* Wob   = (unsigned short*)(ws + 3145984 + 1182720);     // 1,179,648
  unsigned short* WtoT  = (unsigned short*)(ws + 3145984 + 2362368);     // 1,179,648

  k_detect<<<1, 64, 0, stream>>>((const unsigned int*)X, flag);
  k_convert<<<6144, 256, 0, stream>>>(X, Xb, 1572864, flag);
  k_convert<<<288, 256, 0, stream>>>(Wqk, Wqkb, 73728, flag);
  k_convert<<<288, 256, 0, stream>>>(Wv, Wvb, 73728, flag);
  k_build_wrot<<<1152, 256, 0, stream>>>(Wqk, rot, WrotT, flag);
  k_bucket<<<dim3(128, 4), 512, 0, stream>>>(X, WrotT, cls, flag);
  k_sort<<<48, 1024, 0, stream>>>(cls, stick);
  k_gemm_mfma<<<dim3(128, 6), 256, 0, stream>>>(Xb, Wqkb, nullptr, qk, 1, 0, flag);
  k_gemm_mfma<<<dim3(128, 6), 256, 0, stream>>>(Xb, Wvb,  nullptr, v,  1, 0, flag);
  k_norm<<<6144, 256, 0, stream>>>(qk, nk);
  k_attn_mfma<<<3072, 256, 0, stream>>>(qk, v, stick, mask, nk, o_r, lse_r, flag);
  // folded output projection: Wcomb = Wo·Wto via MFMA, bcomb = Wo·bto + bo
  k_convert<<<288, 256, 0, stream>>>(Wo, Wob, 73728, flag);
  k_transpose_cvt<<<144, 256, 0, stream>>>(Wto, WtoT, flag);
  k_bias_fold<<<192, 256, 0, stream>>>(Wo, bto, bo, bcomb, flag);
  k_gemm_mfma<<<dim3(6, 6), 256, 0, stream>>>(Wob, WtoT, nullptr, Wcomb, 0, 0, flag);
  k_combine<<<6144, 256, 0, stream>>>(o_r, lse_r, attn);
  k_gemm_mfma<<<dim3(128, 6), 256, 0, stream>>>(attn, Wcomb, bcomb, d_out, 0, 1, flag);
}

// Round 12
// 606.681 us; speedup vs baseline: 1.0249x; 1.0249x over previous
//
#include <hip/hip_runtime.h>
#include <hip/hip_bf16.h>
#include <math.h>

// ReformerAttention (LSH attention) on MI355X — MFMA + parallel sort + f64-MFMA bucket.
// B=4 T=4096 HID=768 H=12 D=64 n_hashes=2 n_buckets=32 bucket=128.
//
// BEST-MEASURED CONFIGURATION (round 9, 613.3 us). Per-kernel provenance:
//  - k_bucket: round-2 schedule (172.9-176.7 us, MfmaUtil ~74). PINNED: five
//    structural variants (occupancy, barrier cadence, footprint, conflict-free
//    LDS, direct-A global) all landed 173-191 us => ~74% f64-MFMA util is this
//    kernel's structural ceiling.
//  - k_attn_mfma: Q-hoist + LDS-alias (round 6; ~175 us). T14 prefetch (r5)
//    regressed it; pinned.
//  - k_gemm_mfma: round-6 reg-prefetch form. gload_lds depth-0 (r7) regressed;
//    pinned.
//  - Output projections FOLDED: (attn@Wto^T+bto)@Wo^T+bo == attn@(Wo·Wto)^T
//    + (Wo·bto+bo); Wcomb via the MFMA GEMM itself, bcomb f32 wave-reduce.
//
// Workspace layout (bytes), peak 103,809,280:
//   0           flag   256
//   256         stick  u16[48][8192]        786,432
//   786,688     lse_r  f32[48*2][4096]    1,572,864
//   2,359,552   nk     f32[48][4096]        786,432
//   3,145,984   qk     bf16[48][4096][64] 25,165,824  (after k_attn: Wcomb/bcomb/Wob/WtoT)
//   28,311,808  v      bf16[48][4096][64] 25,165,824  (later attn)
//   53,477,632  o_r    bf16[96][4096][64] 50,331,648
//   overlays inside o_r (dead before k_attn): WrotT/cls/Wqkb/Wvb/Xb

typedef __attribute__((ext_vector_type(8))) short bf16x8;
typedef __attribute__((ext_vector_type(4))) float f32x4;
typedef __attribute__((ext_vector_type(4))) double f64x4;

__device__ __forceinline__ float bf_lo(unsigned int w) { return __uint_as_float(w << 16); }
__device__ __forceinline__ float bf_hi(unsigned int w) { return __uint_as_float(w & 0xffff0000u); }
__device__ __forceinline__ float load_in(const void* p, size_t i, bool f32) {
  return f32 ? ((const float*)p)[i]
             : __bfloat162float(((const __hip_bfloat16*)p)[i]);
}
__device__ __forceinline__ unsigned short f2bf(float x) {
  __hip_bfloat16 h = __float2bfloat16(x);
  return *reinterpret_cast<unsigned short*>(&h);
}
__device__ __forceinline__ float bf2f(unsigned short u) { return __uint_as_float(((unsigned int)u) << 16); }

// ---------------------------------------------------------------- dtype detect
__global__ void k_detect(const unsigned int* __restrict__ X, int* __restrict__ flag) {
  if (threadIdx.x == 0 && blockIdx.x == 0) {
    int vote = 0;
    for (int i = 0; i < 64; ++i) {
      unsigned int e = (X[i] >> 7) & 0xffu;
      vote += (e >= 100u && e <= 141u) ? 1 : 0;
    }
    *flag = (vote < 32) ? 1 : 0;   // 1 => inputs are f32
  }
}

// ---------------------------------------------------------------- convert input -> bf16 (x8 vectorized)
__global__ __launch_bounds__(256) void k_convert(
    const void* __restrict__ src, unsigned short* __restrict__ dst, int n8,
    const int* __restrict__ flag) {
  const bool f32in = (*flag != 0);
  int i = blockIdx.x * 256 + threadIdx.x;
  if (i >= n8) return;
  if (f32in) {
    const float4* s = (const float4*)src + (size_t)i * 2;
    float4 a = s[0], b = s[1];
    union { unsigned short u[8]; uint4 v; } o;
    o.u[0] = f2bf(a.x); o.u[1] = f2bf(a.y); o.u[2] = f2bf(a.z); o.u[3] = f2bf(a.w);
    o.u[4] = f2bf(b.x); o.u[5] = f2bf(b.y); o.u[6] = f2bf(b.z); o.u[7] = f2bf(b.w);
    ((uint4*)dst)[i] = o.v;
  } else {
    ((uint4*)dst)[i] = ((const uint4*)src)[i];
  }
}

// ---------------------------------------------------------------- transpose + convert (Wto -> WtoT bf16)
__global__ __launch_bounds__(256) void k_transpose_cvt(
    const void* __restrict__ Wto, unsigned short* __restrict__ WtoT,
    const int* __restrict__ flag) {
  const bool f32in = (*flag != 0);
  __shared__ unsigned short T[64][65];
  const int bx = blockIdx.x % 12, by = blockIdx.x / 12;
  const int p0 = by * 64, n0 = bx * 64;
  const int rw = threadIdx.x >> 6, lane = threadIdx.x & 63;
  #pragma unroll
  for (int pass = 0; pass < 16; ++pass) {
    int row = pass * 4 + rw;
    T[row][lane] = f2bf(load_in(Wto, (size_t)(p0 + row) * 768 + n0 + lane, f32in));
  }
  __syncthreads();
  #pragma unroll
  for (int pass = 0; pass < 16; ++pass) {
    int row = pass * 4 + rw;
    WtoT[(size_t)(n0 + row) * 768 + p0 + lane] = T[lane][row];
  }
}

// ---------------------------------------------------------------- folded bias (f32, raw weights)
__global__ __launch_bounds__(256) void k_bias_fold(
    const void* __restrict__ Wo, const void* __restrict__ bto,
    const void* __restrict__ bo, float* __restrict__ bcomb,
    const int* __restrict__ flag) {
  const bool f32in = (*flag != 0);
  const int n = blockIdx.x * 4 + (threadIdx.x >> 6);
  const int lane = threadIdx.x & 63;
  float s = 0.f;
  #pragma unroll
  for (int i = 0; i < 12; ++i) {
    int j = lane + i * 64;
    s = fmaf(load_in(Wo, (size_t)n * 768 + j, f32in), load_in(bto, j, f32in), s);
  }
  #pragma unroll
  for (int off = 1; off < 64; off <<= 1) s += __shfl_xor(s, off, 64);
  if (lane == 0) bcomb[n] = s + load_in(bo, n, f32in);
}

// ---------------------------------------------------------------- fold rotations (f64)
__global__ __launch_bounds__(256) void k_build_wrot(
    const void* __restrict__ Wqk, const void* __restrict__ rot,
    double* __restrict__ WrotT, const int* __restrict__ flag) {
  const bool f32in = (*flag != 0);
  int idx = blockIdx.x * 256 + threadIdx.x;
  if (idx >= 768 * 384) return;
  int row = idx % 384;
  int c   = idx / 384;
  int hh = row >> 5, hi = row & 31;
  double s = 0.0;
  for (int f = 0; f < 64; ++f) {
    double rv = (double)load_in(rot, f * 32 + hi, f32in);
    double wv = (double)load_in(Wqk, (size_t)(hh * 64 + f) * 768 + c, f32in);
    s = fma(rv, wv, s);
  }
  WrotT[(size_t)c * 384 + row] = s;
}

// ---------------------------------------------------------------- bucket scores (f64 MFMA GEMM) + argmax
// Round-2 configuration (best measured: 172.9 us, MfmaUtil ~74): BM=128 BN=96
// BK=16, 512 thr = 8 waves; wave w owns rows [w*16, w*16+16) x 96 cols
// (6 N-tiles), acc = 6 x double4. Grid 128x4. LDS double-buffered staging,
// one barrier per K-step. 58,368 B LDS -> 2 blocks/CU. PINNED.
//
// D-layout determined at RUNTIME by two probe MFMAs (rowid/colid per acc
// register) — the f64 16x16x4 C/D register mapping is not among the
// HW-verified gfx950 layouts and the assumed mapping failed in round 0.
__global__ __launch_bounds__(512) void k_bucket(
    const void* __restrict__ X, const double* __restrict__ WrotT,
    unsigned char* __restrict__ cls, const int* __restrict__ flag) {
  const bool f32in = (*flag != 0);
  __shared__ double SH[7296];          // 58,368 B
  // staging buffers: Xs[b] = SH + b*2080  ([16][130], [k][m] transposed)
  //                  Ws[b] = SH + 4160 + b*1568  ([16][98], [k][n])
  double* Sc = SH;                     // [96][66] epilogue union
  const int tid = threadIdx.x;
  const int M0 = blockIdx.x * 128;
  const int N0 = blockIdx.y * 96;
  const int w = tid >> 6, lane = tid & 63;
  const int l15 = lane & 15, lq = lane >> 4;
  const int sr = tid >> 2, sh2 = tid & 3;          // X staging: row, k-quarter
  const int wk = tid >> 5, wn3 = (tid & 31) * 3;   // W staging: k-row, 3-col group

  f64x4 acc[6];
  #pragma unroll
  for (int j = 0; j < 6; ++j) acc[j] = (f64x4){0.0, 0.0, 0.0, 0.0};

  // ---- runtime D-layout probe (layout-agnostic epilogue) ----
  int rowid[4], colid[4];
  {
    f64x4 zz = (f64x4){0.0, 0.0, 0.0, 0.0};
    f64x4 pr = __builtin_amdgcn_mfma_f64_16x16x4f64(
        (double)l15, (lq == 0) ? 1.0 : 0.0, zz, 0, 0, 0);
    f64x4 pc = __builtin_amdgcn_mfma_f64_16x16x4f64(
        (lq == 0) ? 1.0 : 0.0, (double)l15, zz, 0, 0, 0);
    #pragma unroll
    for (int r = 0; r < 4; ++r) {
      rowid[r] = (int)pr[r];
      colid[r] = (int)pc[r];
    }
  }

  // register prefetch (global -> reg -> LDS, overlapped with MFMA)
  double xv[4];
  double wvv[3];
  auto load_chunk = [&](int k0) {
    size_t base = (size_t)(M0 + sr) * 768 + k0 + sh2 * 4;
    if (f32in) {
      float4 f0 = *(const float4*)((const float*)X + base);
      xv[0] = f0.x; xv[1] = f0.y; xv[2] = f0.z; xv[3] = f0.w;
    } else {
      uint2 u = *(const uint2*)((const unsigned short*)X + base);
      xv[0] = (double)bf_lo(u.x); xv[1] = (double)bf_hi(u.x);
      xv[2] = (double)bf_lo(u.y); xv[3] = (double)bf_hi(u.y);
    }
    const double* wp = WrotT + (size_t)(k0 + wk) * 384 + N0 + wn3;
    wvv[0] = wp[0]; wvv[1] = wp[1]; wvv[2] = wp[2];
  };
  auto store_stage = [&](int bsel) {
    double* Xs = SH + bsel * 2080;
    double* Ws = SH + 4160 + bsel * 1568;
    #pragma unroll
    for (int j = 0; j < 4; ++j) Xs[(sh2 * 4 + j) * 130 + sr] = xv[j];
    Ws[wk * 98 + wn3]     = wvv[0];
    Ws[wk * 98 + wn3 + 1] = wvv[1];
    Ws[wk * 98 + wn3 + 2] = wvv[2];
  };

  load_chunk(0);
  store_stage(0);
  __syncthreads();
  for (int t = 0; t < 48; ++t) {
    const double* Xs = SH + (t & 1) * 2080;
    const double* Ws = SH + 4160 + (t & 1) * 1568;
    if (t < 47) load_chunk((t + 1) * 16);
    #pragma unroll
    for (int kq = 0; kq < 4; ++kq) {
      // A frag: lane holds X[row = w*16 + l15][k = kq*4 + lq]
      double a = Xs[(kq * 4 + lq) * 130 + w * 16 + l15];
      // B frag: lane holds WrotT[k = kq*4 + lq][col = nt*16 + l15]
      const double* wr = &Ws[(kq * 4 + lq) * 98 + l15];
      #pragma unroll
      for (int nt = 0; nt < 6; ++nt)
        acc[nt] = __builtin_amdgcn_mfma_f64_16x16x4f64(a, wr[nt * 16], acc[nt], 0, 0, 0);
    }
    if (t < 47) store_stage((t & 1) ^ 1);
    __syncthreads();
  }

  // epilogue: two 64-token chunks through Sc, then first-index-wins argmax.
  #pragma unroll
  for (int chunk = 0; chunk < 2; ++chunk) {
    __syncthreads();
    if ((w >> 2) == chunk) {
      int lr = (w & 3) * 16;
      #pragma unroll
      for (int nt = 0; nt < 6; ++nt)
        #pragma unroll
        for (int r = 0; r < 4; ++r)
          Sc[(nt * 16 + colid[r]) * 66 + lr + rowid[r]] = acc[nt][r];
    }
    __syncthreads();
    for (int task = tid; task < 384; task += 512) {
      int g = task >> 6, tok = task & 63;
      const double* s = &Sc[(g * 16) * 66 + tok];
      double mx = -1.0e300;
      #pragma unroll
      for (int i = 0; i < 16; ++i) {
        double a = s[i * 66];
        mx = fmax(mx, fmax(a, -a));
      }
      int amax = 0;
      #pragma unroll
      for (int i = 15; i >= 0; --i) if (-s[i * 66] == mx) amax = 16 + i;
      #pragma unroll
      for (int i = 15; i >= 0; --i) if (s[i * 66] == mx) amax = i;
      int m = M0 + chunk * 64 + tok;
      int b = m >> 12, t = m & 4095;
      int gg = blockIdx.y * 6 + g, hh = gg >> 1, h = gg & 1;
      cls[(size_t)(b * 12 + hh) * 8192 + h * 4096 + t] = (unsigned char)(h * 32 + amax);
    }
  }
}

// ---------------------------------------------------------------- parallel stable counting sort
__global__ __launch_bounds__(1024) void k_sort(
    const unsigned char* __restrict__ clsg,
    unsigned short* __restrict__ stick) {
  __shared__ unsigned short cntg[128 * 64];
  __shared__ int classbase[64];
  const int row = blockIdx.x;
  const int tid = threadIdx.x;
  const int wave = tid >> 6, lane = tid & 63;
  const unsigned char* cr = clsg + ((size_t)row << 13);

  for (int i = tid; i < 128 * 64 / 2; i += 1024) ((uint32_t*)cntg)[i] = 0;
  __syncthreads();

  unsigned char myc[8], myrank[8];
  const unsigned long long ltmask = (lane == 0) ? 0ull : (~0ull >> (64 - lane));
  #pragma unroll
  for (int chunk = 0; chunk < 8; ++chunk) {
    int g = chunk * 16 + wave;
    int j = g * 64 + lane;
    int c = cr[j];
    unsigned long long same = ~0ull;
    #pragma unroll
    for (int bit = 0; bit < 6; ++bit) {
      unsigned long long bm = __ballot((c >> bit) & 1);
      same &= ((c >> bit) & 1) ? bm : ~bm;
    }
    int rank = __popcll(same & ltmask);
    if (rank == 0) cntg[g * 64 + c] = (unsigned short)__popcll(same);
    myc[chunk] = (unsigned char)c;
    myrank[chunk] = (unsigned char)rank;
  }
  __syncthreads();
  if (tid < 64) {
    int run = 0;
    for (int g = 0; g < 128; ++g) {
      int t = cntg[g * 64 + tid];
      cntg[g * 64 + tid] = (unsigned short)run;
      run += t;
    }
    classbase[tid] = run;
  }
  __syncthreads();
  if (tid == 0) {
    int run = 0;
    for (int c = 0; c < 64; ++c) { int t = classbase[c]; classbase[c] = run; run += t; }
  }
  __syncthreads();
  unsigned short* out = stick + ((size_t)row << 13);
  #pragma unroll
  for (int chunk = 0; chunk < 8; ++chunk) {
    int g = chunk * 16 + wave;
    int j = g * 64 + lane;
    int c = myc[chunk];
    int pos = classbase[c] + cntg[g * 64 + c] + myrank[chunk];
    out[pos] = (unsigned short)j;
  }
}

// ---------------------------------------------------------------- MFMA GEMM, K=768
// Round-6 form (best measured): padded LDS [128][40], depth-1 register
// prefetch. bias (when non-null) is ALWAYS f32.
__global__ __launch_bounds__(256) void k_gemm_mfma(
    const unsigned short* __restrict__ A, const unsigned short* __restrict__ W,
    const float* __restrict__ bias, void* __restrict__ Cout,
    int layout, int out_ext, const int* __restrict__ flag) {
  const bool f32in = (*flag != 0);
  const bool oF32 = out_ext && f32in;
  __shared__ unsigned short As[128 * 40];
  __shared__ unsigned short Bs[128 * 40];
  const int tid = threadIdx.x;
  const int bm = blockIdx.x, bn = blockIdx.y;
  const int w = tid >> 6, lane = tid & 63;
  const int l15 = lane & 15, lq = lane >> 4;
  const int wm = (w >> 1) * 64, wn = (w & 1) * 64;
  const int r4 = tid >> 2, c4 = tid & 3;
  const unsigned short* Ag = A + (size_t)(bm * 128 + r4) * 768 + c4 * 8;
  const unsigned short* Bg = W + (size_t)(bn * 128 + r4) * 768 + c4 * 8;
  f32x4 acc[4][4];
  #pragma unroll
  for (int i = 0; i < 4; ++i)
    #pragma unroll
    for (int j = 0; j < 4; ++j) acc[i][j] = (f32x4){0.f, 0.f, 0.f, 0.f};
  uint4 pa0 = *(const uint4*)(Ag);
  uint4 pa1 = *(const uint4*)(Ag + 64 * 768);
  uint4 pb0 = *(const uint4*)(Bg);
  uint4 pb1 = *(const uint4*)(Bg + 64 * 768);
  for (int kt = 0; kt < 24; ++kt) {
    __syncthreads();
    *(uint4*)&As[r4 * 40 + c4 * 8] = pa0;
    *(uint4*)&As[(r4 + 64) * 40 + c4 * 8] = pa1;
    *(uint4*)&Bs[r4 * 40 + c4 * 8] = pb0;
    *(uint4*)&Bs[(r4 + 64) * 40 + c4 * 8] = pb1;
    __syncthreads();
    if (kt < 23) {
      int off = (kt + 1) * 32;
      pa0 = *(const uint4*)(Ag + off);
      pa1 = *(const uint4*)(Ag + 64 * 768 + off);
      pb0 = *(const uint4*)(Bg + off);
      pb1 = *(const uint4*)(Bg + 64 * 768 + off);
    }
    bf16x8 af[4], bfr[4];
    #pragma unroll
    for (int mt = 0; mt < 4; ++mt)
      af[mt] = *(const bf16x8*)&As[(wm + mt * 16 + l15) * 40 + lq * 8];
    #pragma unroll
    for (int nt = 0; nt < 4; ++nt)
      bfr[nt] = *(const bf16x8*)&Bs[(wn + nt * 16 + l15) * 40 + lq * 8];
    #pragma unroll
    for (int mt = 0; mt < 4; ++mt)
      #pragma unroll
      for (int nt = 0; nt < 4; ++nt)
        acc[mt][nt] = __builtin_amdgcn_mfma_f32_16x16x32_bf16(af[mt], bfr[nt], acc[mt][nt], 0, 0, 0);
  }
  #pragma unroll
  for (int mt = 0; mt < 4; ++mt) {
    #pragma unroll
    for (int nt = 0; nt < 4; ++nt) {
      #pragma unroll
      for (int reg = 0; reg < 4; ++reg) {
        int m = bm * 128 + wm + mt * 16 + lq * 4 + reg;
        int n = bn * 128 + wn + nt * 16 + l15;
        float val = acc[mt][nt][reg];
        if (bias != nullptr) val += bias[n];
        if (layout == 0) {
          size_t addr = (size_t)m * 768 + n;
          if (oF32) ((float*)Cout)[addr] = val;
          else      ((unsigned short*)Cout)[addr] = f2bf(val);
        } else {
          int b2 = m >> 12, t2 = m & 4095, hh = n >> 6, f = n & 63;
          ((unsigned short*)Cout)[((((size_t)(b2 * 12 + hh)) << 12) + t2) * 64 + f] = f2bf(val);
        }
      }
    }
  }
}

// ---------------------------------------------------------------- key norms
__global__ __launch_bounds__(256) void k_norm(
    const unsigned short* __restrict__ qk, float* __restrict__ nk) {
  int row = blockIdx.x * 32 + (threadIdx.x >> 3);
  int cs = threadIdx.x & 7;
  const uint4* p = (const uint4*)(qk + (size_t)row * 64);
  uint4 wv = p[cs];
  float s = 0.f;
  float e;
  e = bf_lo(wv.x); s += e * e;  e = bf_hi(wv.x); s += e * e;
  e = bf_lo(wv.y); s += e * e;  e = bf_hi(wv.y); s += e * e;
  e = bf_lo(wv.z); s += e * e;  e = bf_hi(wv.z); s += e * e;
  e = bf_lo(wv.w); s += e * e;  e = bf_hi(wv.w); s += e * e;
  s += __shfl_xor(s, 1, 64);
  s += __shfl_xor(s, 2, 64);
  s += __shfl_xor(s, 4, 64);
  if (cs == 0) nk[row] = 1.0f / fmaxf(sqrtf(s), 1e-12f);
}

// ---------------------------------------------------------------- MFMA LSH attention
// Q-hoist + LDS aliasing for occupancy: Q fragments are loop-invariant, so
// they are read into 16 VGPRs once after Q staging; the Qs LDS region is then
// reused as Ps/Vs. LDS 37.5 KB => 4 blocks/CU. MFMA order bit-identical.
__global__ __launch_bounds__(256) void k_attn_mfma(
    const unsigned short* __restrict__ qk,
    const unsigned short* __restrict__ vv,
    const unsigned short* __restrict__ stick,
    const void* __restrict__ mask,
    const float* __restrict__ nk,
    unsigned short* __restrict__ o_r,
    float* __restrict__ lse_r,
    const int* __restrict__ flag) {
  const bool f32in = (*flag != 0);
  __shared__ unsigned short QPs[128 * 72];   // Q staging, then P matrix / V staging
  __shared__ unsigned short Ks[64 * 72];
  __shared__ unsigned short Vt[64 * 72];
  __shared__ unsigned short Tq[128];
  __shared__ unsigned short Tkv[64];
  __shared__ float Nkv[64];
  unsigned short* Qs = QPs;
  unsigned short* Ps = QPs;
  unsigned short* Vs = QPs;

  const int tid = threadIdx.x;
  const int bh = blockIdx.x >> 6;
  const int ci = blockIdx.x & 63;
  const int b  = bh / 12;
  const int prev = (ci + 63) & 63;
  const int w = tid >> 6, lane = tid & 63;
  const int l15 = lane & 15, lq = lane >> 4;
  const unsigned short* srow = stick + ((size_t)bh << 13);
  const int jrow = tid >> 3, cs = tid & 7;

  #pragma unroll
  for (int pass = 0; pass < 4; ++pass) {
    int r = jrow + pass * 32;
    int s = srow[ci * 128 + r];
    int t = s & 4095;
    uint4 qw = ((const uint4*)(qk + ((((size_t)bh << 12) + t) << 6)))[cs];
    *(uint4*)&Qs[r * 72 + cs * 8] = qw;
    if (cs == 0) {
      float mv = load_in(mask, b * 4096 + t, f32in);
      Tq[r] = (unsigned short)(s | ((mv != 0.0f) ? 0 : 0x8000));
    }
  }
  __syncthreads();

  // ---- Q-hoist: loop-invariant Q fragments into registers ----
  bf16x8 qf[2][2];   // [ks][mt]
  #pragma unroll
  for (int ks = 0; ks < 2; ++ks)
    #pragma unroll
    for (int mt = 0; mt < 2; ++mt)
      qf[ks][mt] = *(const bf16x8*)&Qs[(w * 32 + mt * 16 + l15) * 72 + ks * 32 + lq * 8];

  unsigned short tqr[2][4];
  #pragma unroll
  for (int mt = 0; mt < 2; ++mt)
    #pragma unroll
    for (int reg = 0; reg < 4; ++reg)
      tqr[mt][reg] = Tq[w * 32 + mt * 16 + lq * 4 + reg];

  float m_run[2][4], l_run[2][4];
  f32x4 oacc[2][4];
  #pragma unroll
  for (int mt = 0; mt < 2; ++mt)
    #pragma unroll
    for (int reg = 0; reg < 4; ++reg) { m_run[mt][reg] = -3.0e38f; l_run[mt][reg] = 0.0f; }
  #pragma unroll
  for (int mt = 0; mt < 2; ++mt)
    #pragma unroll
    for (int nto = 0; nto < 4; ++nto) oacc[mt][nto] = (f32x4){0.f, 0.f, 0.f, 0.f};

  for (int kt = 0; kt < 4; ++kt) {
    __syncthreads();   // all waves done with Qs fragments (kt=0) / prev Ps+Vt (kt>0)
    #pragma unroll
    for (int pass = 0; pass < 2; ++pass) {
      int j = jrow + pass * 32;
      int chunk = (kt < 2) ? ci : prev;
      int s = srow[chunk * 128 + (kt & 1) * 64 + j];
      int t = s & 4095;
      const uint4* kb = (const uint4*)(qk + ((((size_t)bh << 12) + t) << 6));
      *(uint4*)&Ks[j * 72 + cs * 8] = kb[cs];
      const uint4* vb = (const uint4*)(vv + ((((size_t)bh << 12) + t) << 6));
      int sw = (cs ^ (j & 7) ^ (j >> 3)) & 7;
      *(uint4*)&Vs[j * 72 + sw * 8] = vb[cs];
      if (cs == 0) {
        float mv = load_in(mask, b * 4096 + t, f32in);
        Tkv[j] = (unsigned short)(t | ((mv != 0.0f) ? 0 : 0x8000));
        Nkv[j] = nk[((size_t)bh << 12) + t] * 0.125f;
      }
    }
    __syncthreads();

    #pragma unroll
    for (int i = 0; i < 8; ++i) {
      int cp = w * 8 + i;
      int q8 = cp >> 2;
      int sw = (q8 ^ (lane & 7) ^ (lane >> 3)) & 7;
      uint32_t wv = *(const uint32_t*)&Vs[lane * 72 + sw * 8 + ((2 * cp) & 7)];
      Vt[(2 * cp) * 72 + lane]     = (unsigned short)(wv & 0xffff);
      Vt[(2 * cp + 1) * 72 + lane] = (unsigned short)(wv >> 16);
    }

    f32x4 sacc[2][4];
    #pragma unroll
    for (int mt = 0; mt < 2; ++mt)
      #pragma unroll
      for (int nt = 0; nt < 4; ++nt) sacc[mt][nt] = (f32x4){0.f, 0.f, 0.f, 0.f};
    #pragma unroll
    for (int ks = 0; ks < 2; ++ks) {
      #pragma unroll
      for (int nt = 0; nt < 4; ++nt) {
        bf16x8 bfr = *(const bf16x8*)&Ks[(nt * 16 + l15) * 72 + ks * 32 + lq * 8];
        #pragma unroll
        for (int mt = 0; mt < 2; ++mt)
          sacc[mt][nt] = __builtin_amdgcn_mfma_f32_16x16x32_bf16(qf[ks][mt], bfr, sacc[mt][nt], 0, 0, 0);
      }
    }

    unsigned short tkc[4];
    float nkc[4];
    #pragma unroll
    for (int nt = 0; nt < 4; ++nt) {
      tkc[nt] = Tkv[nt * 16 + l15];
      nkc[nt] = Nkv[nt * 16 + l15];
    }
    float dv[2][4][4];
    #pragma unroll
    for (int mt = 0; mt < 2; ++mt)
      #pragma unroll
      for (int nt = 0; nt < 4; ++nt)
        #pragma unroll
        for (int reg = 0; reg < 4; ++reg) {
          float x = sacc[mt][nt][reg] * nkc[nt];
          unsigned short ts = tqr[mt][reg];
          if (((tkc[nt] | ts) & 0x8000) != 0) x = -1.0e9f;
          if (((tkc[nt] ^ ts) & 0x0fff) == 0) x = -5.0e4f;
          dv[mt][nt][reg] = x;
        }
    float mn[2][4], scv[2][4];
    #pragma unroll
    for (int mt = 0; mt < 2; ++mt)
      #pragma unroll
      for (int reg = 0; reg < 4; ++reg) {
        float rm = fmaxf(fmaxf(dv[mt][0][reg], dv[mt][1][reg]),
                         fmaxf(dv[mt][2][reg], dv[mt][3][reg]));
        rm = fmaxf(rm, __shfl_xor(rm, 1, 64));
        rm = fmaxf(rm, __shfl_xor(rm, 2, 64));
        rm = fmaxf(rm, __shfl_xor(rm, 4, 64));
        rm = fmaxf(rm, __shfl_xor(rm, 8, 64));
        float mnew = fmaxf(m_run[mt][reg], rm);
        scv[mt][reg] = __expf(m_run[mt][reg] - mnew);
        m_run[mt][reg] = mnew;
        mn[mt][reg] = mnew;
      }
    #pragma unroll
    for (int mt = 0; mt < 2; ++mt)
      #pragma unroll
      for (int nt = 0; nt < 4; ++nt)
        #pragma unroll
        for (int reg = 0; reg < 4; ++reg)
          dv[mt][nt][reg] = __expf(dv[mt][nt][reg] - mn[mt][reg]);
    #pragma unroll
    for (int mt = 0; mt < 2; ++mt)
      #pragma unroll
      for (int reg = 0; reg < 4; ++reg) {
        float rs = ((dv[mt][0][reg] + dv[mt][1][reg]) + (dv[mt][2][reg] + dv[mt][3][reg]));
        rs += __shfl_xor(rs, 1, 64);
        rs += __shfl_xor(rs, 2, 64);
        rs += __shfl_xor(rs, 4, 64);
        rs += __shfl_xor(rs, 8, 64);
        l_run[mt][reg] = l_run[mt][reg] * scv[mt][reg] + rs;
      }
    #pragma unroll
    for (int mt = 0; mt < 2; ++mt)
      #pragma unroll
      for (int nto = 0; nto < 4; ++nto)
        #pragma unroll
        for (int reg = 0; reg < 4; ++reg)
          oacc[mt][nto][reg] *= scv[mt][reg];

    __syncthreads();

    #pragma unroll
    for (int mt = 0; mt < 2; ++mt)
      #pragma unroll
      for (int nt = 0; nt < 4; ++nt)
        #pragma unroll
        for (int reg = 0; reg < 4; ++reg)
          Ps[w * 2304 + (mt * 16 + lq * 4 + reg) * 72 + nt * 16 + l15] = f2bf(dv[mt][nt][reg]);

    #pragma unroll
    for (int ks = 0; ks < 2; ++ks) {
      bf16x8 pf[2];
      #pragma unroll
      for (int mt = 0; mt < 2; ++mt)
        pf[mt] = *(const bf16x8*)&Ps[w * 2304 + (mt * 16 + l15) * 72 + ks * 32 + lq * 8];
      #pragma unroll
      for (int nto = 0; nto < 4; ++nto) {
        bf16x8 vf = *(const bf16x8*)&Vt[(nto * 16 + l15) * 72 + ks * 32 + lq * 8];
        #pragma unroll
        for (int mt = 0; mt < 2; ++mt)
          oacc[mt][nto] = __builtin_amdgcn_mfma_f32_16x16x32_bf16(pf[mt], vf, oacc[mt][nto], 0, 0, 0);
      }
    }
  }

  float invl[2][4];
  #pragma unroll
  for (int mt = 0; mt < 2; ++mt)
    #pragma unroll
    for (int reg = 0; reg < 4; ++reg) {
      float lr = l_run[mt][reg];
      invl[mt][reg] = 1.0f / lr;
      if (l15 == 0) {
        int Rr = w * 32 + mt * 16 + lq * 4 + reg;
        int s = Tq[Rr];
        int tq0 = s & 4095, rq0 = (s >> 12) & 1;
        lse_r[(((size_t)(bh * 2 + rq0)) << 12) + tq0] = m_run[mt][reg] + __logf(lr);
      }
    }
  #pragma unroll
  for (int mt = 0; mt < 2; ++mt)
    #pragma unroll
    for (int nto = 0; nto < 4; ++nto)
      #pragma unroll
      for (int reg = 0; reg < 4; ++reg)
        Ps[w * 2304 + (mt * 16 + lq * 4 + reg) * 72 + nto * 16 + l15] =
            f2bf(oacc[mt][nto][reg] * invl[mt][reg]);
  #pragma unroll
  for (int pass = 0; pass < 4; ++pass) {
    int rl = pass * 8 + (lane >> 3);
    int s = Tq[w * 32 + rl];
    int tq0 = s & 4095, rq0 = (s >> 12) & 1;
    uint4 ov = *(const uint4*)&Ps[w * 2304 + rl * 72 + (lane & 7) * 8];
    *(uint4*)(o_r + ((((size_t)(bh * 2 + rq0)) << 12) + tq0) * 64 + (lane & 7) * 8) = ov;
  }
}

// ---------------------------------------------------------------- combine hash rounds (x8 vectorized)
__global__ __launch_bounds__(256) void k_combine(
    const unsigned short* __restrict__ o_r,
    const float* __restrict__ lse_r,
    unsigned short* __restrict__ attn) {
  int idx = blockIdx.x * 256 + threadIdx.x;   // over 48*4096*8 groups
  if (idx >= 48 * 4096 * 8) return;
  int f8 = idx & 7;
  int t = (idx >> 3) & 4095;
  int bh = idx >> 15;
  float l0 = lse_r[((size_t)(bh * 2 + 0) << 12) + t];
  float l1 = lse_r[((size_t)(bh * 2 + 1) << 12) + t];
  float mm = fmaxf(l0, l1);
  float e0 = __expf(l0 - mm), e1 = __expf(l1 - mm);
  float inv = 1.0f / (e0 + e1);
  float c0 = e0 * inv, c1 = e1 * inv;
  uint4 v0 = *(const uint4*)(o_r + ((((size_t)(bh * 2 + 0)) << 12) + t) * 64 + f8 * 8);
  uint4 v1 = *(const uint4*)(o_r + ((((size_t)(bh * 2 + 1)) << 12) + t) * 64 + f8 * 8);
  union { unsigned short u[8]; uint4 v; } o;
  const unsigned int* a0 = (const unsigned int*)&v0;
  const unsigned int* a1 = (const unsigned int*)&v1;
  #pragma unroll
  for (int j = 0; j < 4; ++j) {
    float lo = c0 * bf_lo(a0[j]) + c1 * bf_lo(a1[j]);
    float hi = c0 * bf_hi(a0[j]) + c1 * bf_hi(a1[j]);
    o.u[2 * j]     = f2bf(lo);
    o.u[2 * j + 1] = f2bf(hi);
  }
  int b = bh / 12, hh = bh % 12;
  *(uint4*)(attn + ((size_t)(b * 4096 + t)) * 768 + hh * 64 + f8 * 8) = o.v;
}

extern "C" void kernel_launch(void* const* d_in, const int* in_sizes, int n_in,
                              void* d_out, int out_size, void* d_ws, size_t ws_size,
                              hipStream_t stream) {
  (void)in_sizes; (void)n_in; (void)out_size; (void)ws_size;
  const void* X    = d_in[0];
  const void* mask = d_in[1];
  const void* Wqk  = d_in[2];
  const void* Wv   = d_in[3];
  const void* rot  = d_in[4];
  const void* Wto  = d_in[5];
  const void* bto  = d_in[6];
  const void* Wo   = d_in[7];
  const void* bo   = d_in[8];

  char* ws = (char*)d_ws;
  int*            flag  = (int*)(ws);
  unsigned short* stick = (unsigned short*)(ws + 256);
  float*          lse_r = (float*)(ws + 786688);
  float*          nk    = (float*)(ws + 2359552);
  unsigned short* qk    = (unsigned short*)(ws + 3145984);
  unsigned short* v     = (unsigned short*)(ws + 28311808);
  unsigned short* o_r   = (unsigned short*)(ws + 53477632);
  double*         WrotT = (double*)(ws + 53477632);
  unsigned char*  cls   = (unsigned char*)(ws + 55836928);
  unsigned short* Wqkb  = (unsigned short*)(ws + 56230144);
  unsigned short* Wvb   = (unsigned short*)(ws + 57409792);
  unsigned short* Xb    = (unsigned short*)(ws + 58589440);
  unsigned short* attn  = v;
  // fold scratch lives in the dead qk region after k_attn
  unsigned short* Wcomb = (unsigned short*)(ws + 3145984);               // 1,179,648
  float*          bcomb = (float*)(ws + 3145984 + 1179648);              //     3,072
  unsigned short* Wob   = (unsigned short*)(ws + 3145984 + 1182720);     // 1,179,648
  unsigned short* WtoT  = (unsigned short*)(ws + 3145984 + 2362368);     // 1,179,648

  k_detect<<<1, 64, 0, stream>>>((const unsigned int*)X, flag);
  k_convert<<<6144, 256, 0, stream>>>(X, Xb, 1572864, flag);
  k_convert<<<288, 256, 0, stream>>>(Wqk, Wqkb, 73728, flag);
  k_convert<<<288, 256, 0, stream>>>(Wv, Wvb, 73728, flag);
  k_build_wrot<<<1152, 256, 0, stream>>>(Wqk, rot, WrotT, flag);
  k_bucket<<<dim3(128, 4), 512, 0, stream>>>(X, WrotT, cls, flag);
  k_sort<<<48, 1024, 0, stream>>>(cls, stick);
  k_gemm_mfma<<<dim3(128, 6), 256, 0, stream>>>(Xb, Wqkb, nullptr, qk, 1, 0, flag);
  k_gemm_mfma<<<dim3(128, 6), 256, 0, stream>>>(Xb, Wvb,  nullptr, v,  1, 0, flag);
  k_norm<<<6144, 256, 0, stream>>>(qk, nk);
  k_attn_mfma<<<3072, 256, 0, stream>>>(qk, v, stick, mask, nk, o_r, lse_r, flag);
  // folded output projection: Wcomb = Wo·Wto via MFMA, bcomb = Wo·bto + bo
  k_convert<<<288, 256, 0, stream>>>(Wo, Wob, 73728, flag);
  k_transpose_cvt<<<144, 256, 0, stream>>>(Wto, WtoT, flag);
  k_bias_fold<<<192, 256, 0, stream>>>(Wo, bto, bo, bcomb, flag);
  k_gemm_mfma<<<dim3(6, 6), 256, 0, stream>>>(Wob, WtoT, nullptr, Wcomb, 0, 0, flag);
  k_combine<<<6144, 256, 0, stream>>>(o_r, lse_r, attn);
  k_gemm_mfma<<<dim3(128, 6), 256, 0, stream>>>(attn, Wcomb, bcomb, d_out, 0, 1, flag);
}